// Round 15
// baseline (274.274 us; speedup 1.0000x reference)
//
#include <hip/hip_runtime.h>

#define N_NODES 100000
#define N_EDGES 3200000
#define N_LBL   200000
#define C1 128
#define C2 64

// bucketing: nodes grouped by (node >> BSH), 128 nodes per bucket
#define BSH   7
#define NPB   128
#define NBKT  ((N_NODES + NPB - 1) / NPB)   // 782
#define NCB   500                            // placing blocks (2/CU)
#define PPT   512                            // pair_place threads
#define CHUNK (N_EDGES / NCB)                // 6400 edges per block (exact)
#define CAP   4992                           // slots per bucket (mean 4092, +14 sigma)

#define RSTRIDE 132                          // LDS h1-row stride (128 + 4 pad)
#define BN    32                             // nodes per gemm block (LDS diet)

__device__ __forceinline__ float4 f4add(float4 a, float4 b) {
    return make_float4(a.x + b.x, a.y + b.y, a.z + b.z, a.w + b.w);
}
__device__ __forceinline__ unsigned short f2bf(float f) {
    unsigned int u = __float_as_uint(f);
    u += 0x7fff + ((u >> 16) & 1);           // RNE
    return (unsigned short)(u >> 16);
}
__device__ __forceinline__ float bflo(unsigned int u) {
    return __uint_as_float(u << 16);
}
__device__ __forceinline__ float bfhi(unsigned int u) {
    return __uint_as_float(u & 0xffff0000u);
}

// ---------------------------------------------------------------------------
// k1) bucketize edges into packed u32 (dst_local<<17 | src), fixed-cap buckets.
//     Rank-in-register: ONE LDS atomic per edge. Block 0 additionally packs
//     W2 -> bf16 global buffer (consumed 2 kernels later; no race).
__global__ __launch_bounds__(PPT) void pair_place_kernel(const int* __restrict__ ei,
        int* __restrict__ gcursor, unsigned int* __restrict__ pairs,
        const float* __restrict__ W2, unsigned int* __restrict__ w2p) {
    __shared__ int hist[NBKT];
    __shared__ int cur[NBKT];
    int tid = threadIdx.x;
    if (blockIdx.x == 0) {                   // fold-in: pack W2 to bf16 pairs
        const float2* w2f = (const float2*)W2;
        for (int i = tid; i < C1 * C2 / 2; i += PPT) {
            float2 v = w2f[i];
            w2p[i] = (unsigned int)f2bf(v.x) | ((unsigned int)f2bf(v.y) << 16);
        }
    }
    for (int i = tid; i < NBKT; i += PPT) hist[i] = 0;
    __syncthreads();
    int base = blockIdx.x * CHUNK;
    unsigned int pk[13]; int bkt[13]; int rnk[13];   // CHUNK/PPT = 12.5 -> 13
    #pragma unroll
    for (int k = 0; k < 13; ++k) {
        if (k < 12 || tid < CHUNK - 12 * PPT) {      // k=12 covers 256
            int e = base + k * PPT + tid;
            int s = ei[e], d = ei[N_EDGES + e];
            int b = d >> BSH;
            bkt[k] = b;
            pk[k] = ((unsigned int)(d & (NPB - 1)) << 17) | (unsigned int)s;
            rnk[k] = atomicAdd(&hist[b], 1);
        }
    }
    __syncthreads();
    for (int i = tid; i < NBKT; i += PPT) {
        int h = hist[i];
        cur[i] = h ? (i * CAP + atomicAdd(&gcursor[i], h)) : 0;
    }
    __syncthreads();
    #pragma unroll
    for (int k = 0; k < 13; ++k) {
        if (k < 12 || tid < CHUNK - 12 * PPT) {
            int pos = cur[bkt[k]] + rnk[k];
            pos = min(pos, NBKT * CAP - 1);          // defensive (stat. never)
            pairs[pos] = pk[k];
        }
    }
}

// k2) per-bucket finish: SINGLE pass over pairs (rank-in-register), local scan,
//     offs/ends/inv/xs, then atomic-free placement of srcs.
__global__ __launch_bounds__(512) void bucket_finish_kernel(
        const unsigned int* __restrict__ pairs, const int* __restrict__ gcursor,
        const float4* __restrict__ x, int* __restrict__ offs, int* __restrict__ ends,
        float* __restrict__ inv, float4* __restrict__ xs, int* __restrict__ srcs) {
    __shared__ int deg[NPB];
    __shared__ int nstart[NPB];
    __shared__ int wsum2[2];
    int tid = threadIdx.x;
    int b = blockIdx.x;
    int nbase = b << BSH;
    int eb = b * CAP;
    int ee = eb + min(gcursor[b], CAP);              // gcursor holds the COUNT
    if (tid < NPB) deg[tid] = 0;
    __syncthreads();
    unsigned int pk[10]; int rnk[10];                // CAP/512 = 9.75 -> 10 slots
    #pragma unroll
    for (int k = 0; k < 10; ++k) {
        int j = eb + k * 512 + tid;
        if (j < ee) {
            unsigned int p = pairs[j];
            pk[k] = p;
            rnk[k] = atomicAdd(&deg[p >> 17], 1);
        }
    }
    __syncthreads();
    int v = 0, incl = 0;
    if (tid < NPB) {                                 // waves 0-1: scan 128 degrees
        int lane = tid & 63;
        v = deg[tid];
        incl = v;
        #pragma unroll
        for (int off = 1; off < 64; off <<= 1) {
            int t = __shfl_up(incl, off);
            if (lane >= off) incl += t;
        }
        if (lane == 63) wsum2[tid >> 6] = incl;
    }
    __syncthreads();
    if (tid < NPB) {
        int excl = incl - v + ((tid >= 64) ? wsum2[0] : 0);
        int start = eb + excl;
        nstart[tid] = start;
        int n = nbase + tid;
        if (n < N_NODES) {
            offs[n] = start;
            ends[n] = start + v;
            float iv = rsqrtf((float)(v + 1));
            inv[n] = iv;
            float4 xv = x[n];
            xv.x *= iv; xv.y *= iv; xv.z *= iv; xv.w *= iv;
            xs[n] = xv;
        }
    }
    __syncthreads();
    #pragma unroll
    for (int k = 0; k < 10; ++k) {
        int j = eb + k * 512 + tid;
        if (j < ee) {
            unsigned int p = pk[k];
            srcs[nstart[p >> 17] + rnk[k]] = (int)(p & 0x1FFFFu);
        }
    }
}

// ---------------------------------------------------------------------------
// 3) fused agg1 + gemm1 + gemm2. 32 nodes/block: LDS = w1s+bs+rows+aggt =
//    19.9 KB -> 8 blocks/CU (32 waves, HW max) to hide the Phase-0 gather
//    latency (the kernel's dominant cost). W2 via __ldg (L1-resident 16 KB).
__global__ __launch_bounds__(256) void agg1_gemm12_kernel(
        const float4* __restrict__ xs, const int* __restrict__ offs,
        const int* __restrict__ ends, const int* __restrict__ srcs,
        const float* __restrict__ inv, const float* __restrict__ W1,
        const float* __restrict__ b1, const unsigned int* __restrict__ w2p,
        unsigned short* __restrict__ hs2b) {
    __shared__ float w1s[4 * C1];                    // 2 KB
    __shared__ float bs[C1];                         // 0.5 KB
    __shared__ float rows[BN * RSTRIDE];             // 16.9 KB
    __shared__ float4 aggt[BN];                      // 0.5 KB
    int tid = threadIdx.x;
    int base = blockIdx.x * BN;
    w1s[tid] = W1[tid];                      // W1 is 512 floats, block is 256:
    w1s[tid + 256] = W1[tid + 256];          // each thread loads BOTH halves
    if (tid < C1) bs[tid] = b1[tid];
    // Phase 0: 8 lanes/node x 32 nodes = 256 threads; butterfly xor 1/2/4.
    int nd = tid >> 3, g = tid & 7;
    int n = base + nd;
    {
        float4 acc0 = make_float4(0.f, 0.f, 0.f, 0.f);
        if (n < N_NODES) {
            if (g == 0) acc0 = xs[n];
            int e = ends[n];
            for (int j = offs[n] + g; j < e; j += 8)
                acc0 = f4add(acc0, xs[srcs[j]]);
        }
        #pragma unroll
        for (int w = 1; w <= 4; w <<= 1) {
            acc0.x += __shfl_xor(acc0.x, w); acc0.y += __shfl_xor(acc0.y, w);
            acc0.z += __shfl_xor(acc0.z, w); acc0.w += __shfl_xor(acc0.w, w);
        }
        if (g == 0) aggt[nd] = acc0;
    }
    __syncthreads();          // staging (w1s/bs) + aggt complete
    // Phase A: h1 rows -> LDS. thread = (node nd, part g): c = g + 8*cc
    {
        float s = (n < N_NODES) ? inv[n] : 0.f;
        float4 t = aggt[nd];
        t.x *= s; t.y *= s; t.z *= s; t.w *= s;
        #pragma unroll 8
        for (int cc = 0; cc < 16; ++cc) {
            int c = g + 8 * cc;
            float h = t.x * w1s[c] + t.y * w1s[C1 + c] + t.z * w1s[2 * C1 + c]
                    + t.w * w1s[3 * C1 + c] + bs[c];
            rows[nd * RSTRIDE + c] = fmaxf(h, 0.f);
        }
    }
    __syncthreads();
    // Phase B: 16 col-quads x 16 node-groups (2 nodes each); W2 via __ldg
    // from packed-bf16 global (16 KB, L1-resident, 16-lane-broadcast uint2).
    int q = tid & 15;
    int ng = tid >> 4;
    float4 acc[2];
    acc[0] = make_float4(0.f, 0.f, 0.f, 0.f);
    acc[1] = make_float4(0.f, 0.f, 0.f, 0.f);
    const uint2* w2v = (const uint2*)w2p;
    #pragma unroll 4
    for (int k = 0; k < C1; ++k) {
        uint2 wp = __ldg(w2v + k * 16 + q);
        float wx = bflo(wp.x), wy = bfhi(wp.x);
        float wz = bflo(wp.y), ww = bfhi(wp.y);
        #pragma unroll
        for (int j = 0; j < 2; ++j) {
            float r = rows[(ng * 2 + j) * RSTRIDE + k];
            acc[j].x += r * wx; acc[j].y += r * wy;
            acc[j].z += r * wz; acc[j].w += r * ww;
        }
    }
    #pragma unroll
    for (int j = 0; j < 2; ++j) {
        int m = base + ng * 2 + j;
        if (m < N_NODES) {
            float s = inv[m];
            ushort4 o;
            o.x = f2bf(acc[j].x * s); o.y = f2bf(acc[j].y * s);
            o.z = f2bf(acc[j].z * s); o.w = f2bf(acc[j].w * s);
            *((ushort4*)(hs2b + (size_t)m * C2) + q) = o;
        }
    }
}

// 4) agg2: one 64-lane wave per node; 8 x 16B-chunk lanes x 8 neighbor slots,
//    2-row unroll (16 rows in flight/wave — measured optimum; plateau at
//    ~62.6 us: FETCH 160 MB vs 102 MB compulsory 8-XCD floor, lines fully used).
//    zb = bf16( inv*(hs2[n] + sum hs2[src]) + b2 )
__global__ void agg2_kernel(const unsigned short* __restrict__ hs2b,
                            const int* __restrict__ offs, const int* __restrict__ ends,
                            const int* __restrict__ srcs, const float* __restrict__ inv,
                            const float4* __restrict__ b2,
                            unsigned short* __restrict__ zb) {
    int gid = blockIdx.x * blockDim.x + threadIdx.x;
    int n = gid >> 6;
    if (n >= N_NODES) return;
    int lane = gid & 63;
    int q = lane & 7;           // 16B chunk (8 bf16 channels) within the row
    int g = lane >> 3;          // neighbor slot 0..7
    float acc[8] = {0.f, 0.f, 0.f, 0.f, 0.f, 0.f, 0.f, 0.f};
    if (g == 0) {
        uint4 v = *((const uint4*)(hs2b + (size_t)n * C2) + q);
        acc[0] += bflo(v.x); acc[1] += bfhi(v.x);
        acc[2] += bflo(v.y); acc[3] += bfhi(v.y);
        acc[4] += bflo(v.z); acc[5] += bfhi(v.z);
        acc[6] += bflo(v.w); acc[7] += bfhi(v.w);
    }
    int e = ends[n];
    int j = offs[n] + g;
    for (; j + 8 < e; j += 16) {            // both j and j+8 valid
        int s0 = srcs[j];
        int s1 = srcs[j + 8];
        uint4 v0 = *((const uint4*)(hs2b + (size_t)s0 * C2) + q);
        uint4 v1 = *((const uint4*)(hs2b + (size_t)s1 * C2) + q);
        acc[0] += bflo(v0.x); acc[1] += bfhi(v0.x);
        acc[2] += bflo(v0.y); acc[3] += bfhi(v0.y);
        acc[4] += bflo(v0.z); acc[5] += bfhi(v0.z);
        acc[6] += bflo(v0.w); acc[7] += bfhi(v0.w);
        acc[0] += bflo(v1.x); acc[1] += bfhi(v1.x);
        acc[2] += bflo(v1.y); acc[3] += bfhi(v1.y);
        acc[4] += bflo(v1.z); acc[5] += bfhi(v1.z);
        acc[6] += bflo(v1.w); acc[7] += bfhi(v1.w);
    }
    if (j < e) {
        int s0 = srcs[j];
        uint4 v0 = *((const uint4*)(hs2b + (size_t)s0 * C2) + q);
        acc[0] += bflo(v0.x); acc[1] += bfhi(v0.x);
        acc[2] += bflo(v0.y); acc[3] += bfhi(v0.y);
        acc[4] += bflo(v0.z); acc[5] += bfhi(v0.z);
        acc[6] += bflo(v0.w); acc[7] += bfhi(v0.w);
    }
    #pragma unroll
    for (int k = 0; k < 8; ++k) {
        acc[k] += __shfl_xor(acc[k], 8);
        acc[k] += __shfl_xor(acc[k], 16);
        acc[k] += __shfl_xor(acc[k], 32);
    }
    if (g == 0) {
        float s = inv[n];
        float4 b0 = b2[q * 2], b1v = b2[q * 2 + 1];
        float o0 = acc[0] * s + b0.x,  o1 = acc[1] * s + b0.y;
        float o2 = acc[2] * s + b0.z,  o3 = acc[3] * s + b0.w;
        float o4 = acc[4] * s + b1v.x, o5 = acc[5] * s + b1v.y;
        float o6 = acc[6] * s + b1v.z, o7 = acc[7] * s + b1v.w;
        uint4 w;
        w.x = (unsigned int)f2bf(o0) | ((unsigned int)f2bf(o1) << 16);
        w.y = (unsigned int)f2bf(o2) | ((unsigned int)f2bf(o3) << 16);
        w.z = (unsigned int)f2bf(o4) | ((unsigned int)f2bf(o5) << 16);
        w.w = (unsigned int)f2bf(o6) | ((unsigned int)f2bf(o7) << 16);
        ((uint4*)(zb + (size_t)n * C2))[q] = w;
    }
}

// 5) decode: logits[e] = dot(zb[a], zb[b])   (8 lanes/edge, bf16 rows)
__global__ void decode_kernel(const int* __restrict__ eli,
                              const unsigned short* __restrict__ zb,
                              float* __restrict__ out) {
    int gid = blockIdx.x * blockDim.x + threadIdx.x;
    int e = gid >> 3;
    if (e >= N_LBL) return;
    int q = gid & 7;
    int a = eli[e], b = eli[N_LBL + e];
    uint4 va = ((const uint4*)zb)[(size_t)a * 8 + q];
    uint4 vb = ((const uint4*)zb)[(size_t)b * 8 + q];
    float p = bflo(va.x) * bflo(vb.x) + bfhi(va.x) * bfhi(vb.x)
            + bflo(va.y) * bflo(vb.y) + bfhi(va.y) * bfhi(vb.y)
            + bflo(va.z) * bflo(vb.z) + bfhi(va.z) * bfhi(vb.z)
            + bflo(va.w) * bflo(vb.w) + bfhi(va.w) * bfhi(vb.w);
    p += __shfl_xor(p, 4);
    p += __shfl_xor(p, 2);
    p += __shfl_xor(p, 1);
    if (q == 0) out[e] = p;
}

extern "C" void kernel_launch(void* const* d_in, const int* in_sizes, int n_in,
                              void* d_out, int out_size, void* d_ws, size_t ws_size,
                              hipStream_t stream) {
    const float* x  = (const float*)d_in[0];
    const int*   ei = (const int*)d_in[1];
    const int*  eli = (const int*)d_in[2];
    const float* W1 = (const float*)d_in[3];
    const float* b1 = (const float*)d_in[4];
    const float* W2 = (const float*)d_in[5];
    const float* b2 = (const float*)d_in[6];
    float* out = (float*)d_out;

    // workspace layout (all 16B aligned). Total ~59 MB.
    char* p = (char*)d_ws;
    int*   gcursor = (int*)p;   p += 1024 * 4;
    unsigned int* w2p = (unsigned int*)p; p += (size_t)(C1 * C2 / 2) * 4;  // 16 KB
    int*   offs    = (int*)p;   p += (size_t)N_NODES * 4;
    int*   ends    = (int*)p;   p += (size_t)N_NODES * 4;
    float* inv     = (float*)p; p += (size_t)N_NODES * 4;
    unsigned int* pairs = (unsigned int*)p; p += (size_t)NBKT * CAP * 4;  // 15.6 MB
    int*   srcs    = (int*)p;   p += (size_t)NBKT * CAP * 4;              // 15.6 MB
    float* xs      = (float*)p; p += (size_t)N_NODES * 16;
    unsigned short* hs2b = (unsigned short*)p; p += (size_t)N_NODES * C2 * 2; // 12.8 MB
    unsigned short* zb   = (unsigned short*)p; p += (size_t)N_NODES * C2 * 2; // 12.8 MB

    hipMemsetAsync(gcursor, 0, NBKT * 4, stream);
    pair_place_kernel<<<NCB, PPT, 0, stream>>>(ei, gcursor, pairs, W2, w2p);
    bucket_finish_kernel<<<NBKT, 512, 0, stream>>>(pairs, gcursor, (const float4*)x,
                                                   offs, ends, inv, (float4*)xs, srcs);
    agg1_gemm12_kernel<<<(N_NODES + BN - 1) / BN, 256, 0, stream>>>(
        (const float4*)xs, offs, ends, srcs, inv, W1, b1, w2p, hs2b);
    agg2_kernel<<<((size_t)N_NODES * 64 + 255) / 256, 256, 0, stream>>>(
        hs2b, offs, ends, srcs, inv, (const float4*)b2, zb);
    decode_kernel<<<((size_t)N_LBL * 8 + 255) / 256, 256, 0, stream>>>(eli, zb, out);
}

// Round 16
// 251.876 us; speedup vs baseline: 1.0889x; 1.0889x over previous
//
#include <hip/hip_runtime.h>

#define N_NODES 100000
#define N_EDGES 3200000
#define N_LBL   200000
#define C1 128
#define C2 64

// bucketing: nodes grouped by (node >> BSH), 128 nodes per bucket
#define BSH   7
#define NPB   128
#define NBKT  ((N_NODES + NPB - 1) / NPB)   // 782
#define NCB   500                            // placing blocks (2/CU)
#define PPT   512                            // pair_place threads
#define CHUNK (N_EDGES / NCB)                // 6400 edges per block (exact)
#define CAP   4992                           // slots per bucket (mean 4092, +14 sigma)

#define RSTRIDE 132                          // LDS h1-row stride (128 + 4 pad)

__device__ __forceinline__ float4 f4add(float4 a, float4 b) {
    return make_float4(a.x + b.x, a.y + b.y, a.z + b.z, a.w + b.w);
}
__device__ __forceinline__ unsigned short f2bf(float f) {
    unsigned int u = __float_as_uint(f);
    u += 0x7fff + ((u >> 16) & 1);           // RNE
    return (unsigned short)(u >> 16);
}
__device__ __forceinline__ float bflo(unsigned int u) {
    return __uint_as_float(u << 16);
}
__device__ __forceinline__ float bfhi(unsigned int u) {
    return __uint_as_float(u & 0xffff0000u);
}

// ---------------------------------------------------------------------------
// k1) bucketize edges into packed u32 (dst_local<<17 | src), fixed-cap buckets.
//     Rank-in-register: ONE LDS atomic per edge (DS-pipe atomic throughput is
//     the binding constraint — R6/R7 showed wave count doesn't help).
__global__ __launch_bounds__(PPT) void pair_place_kernel(const int* __restrict__ ei,
        int* __restrict__ gcursor, unsigned int* __restrict__ pairs) {
    __shared__ int hist[NBKT];
    __shared__ int cur[NBKT];
    int tid = threadIdx.x;
    for (int i = tid; i < NBKT; i += PPT) hist[i] = 0;
    __syncthreads();
    int base = blockIdx.x * CHUNK;
    unsigned int pk[13]; int bkt[13]; int rnk[13];   // CHUNK/PPT = 12.5 -> 13
    #pragma unroll
    for (int k = 0; k < 13; ++k) {
        if (k < 12 || tid < CHUNK - 12 * PPT) {      // k=12 covers 256
            int e = base + k * PPT + tid;
            int s = ei[e], d = ei[N_EDGES + e];
            int b = d >> BSH;
            bkt[k] = b;
            pk[k] = ((unsigned int)(d & (NPB - 1)) << 17) | (unsigned int)s;
            rnk[k] = atomicAdd(&hist[b], 1);
        }
    }
    __syncthreads();
    for (int i = tid; i < NBKT; i += PPT) {
        int h = hist[i];
        cur[i] = h ? (i * CAP + atomicAdd(&gcursor[i], h)) : 0;
    }
    __syncthreads();
    #pragma unroll
    for (int k = 0; k < 13; ++k) {
        if (k < 12 || tid < CHUNK - 12 * PPT) {
            int pos = cur[bkt[k]] + rnk[k];
            pos = min(pos, NBKT * CAP - 1);          // defensive (stat. never)
            pairs[pos] = pk[k];
        }
    }
}

// k2) per-bucket finish: SINGLE pass over pairs (rank-in-register), local scan,
//     offs/ends/inv/xs, then atomic-free placement of srcs.
__global__ __launch_bounds__(512) void bucket_finish_kernel(
        const unsigned int* __restrict__ pairs, const int* __restrict__ gcursor,
        const float4* __restrict__ x, int* __restrict__ offs, int* __restrict__ ends,
        float* __restrict__ inv, float4* __restrict__ xs, int* __restrict__ srcs) {
    __shared__ int deg[NPB];
    __shared__ int nstart[NPB];
    __shared__ int wsum2[2];
    int tid = threadIdx.x;
    int b = blockIdx.x;
    int nbase = b << BSH;
    int eb = b * CAP;
    int ee = eb + min(gcursor[b], CAP);              // gcursor holds the COUNT
    if (tid < NPB) deg[tid] = 0;
    __syncthreads();
    unsigned int pk[10]; int rnk[10];                // CAP/512 = 9.75 -> 10 slots
    #pragma unroll
    for (int k = 0; k < 10; ++k) {
        int j = eb + k * 512 + tid;
        if (j < ee) {
            unsigned int p = pairs[j];
            pk[k] = p;
            rnk[k] = atomicAdd(&deg[p >> 17], 1);
        }
    }
    __syncthreads();
    int v = 0, incl = 0;
    if (tid < NPB) {                                 // waves 0-1: scan 128 degrees
        int lane = tid & 63;
        v = deg[tid];
        incl = v;
        #pragma unroll
        for (int off = 1; off < 64; off <<= 1) {
            int t = __shfl_up(incl, off);
            if (lane >= off) incl += t;
        }
        if (lane == 63) wsum2[tid >> 6] = incl;
    }
    __syncthreads();
    if (tid < NPB) {
        int excl = incl - v + ((tid >= 64) ? wsum2[0] : 0);
        int start = eb + excl;
        nstart[tid] = start;
        int n = nbase + tid;
        if (n < N_NODES) {
            offs[n] = start;
            ends[n] = start + v;
            float iv = rsqrtf((float)(v + 1));
            inv[n] = iv;
            float4 xv = x[n];
            xv.x *= iv; xv.y *= iv; xv.z *= iv; xv.w *= iv;
            xs[n] = xv;
        }
    }
    __syncthreads();
    #pragma unroll
    for (int k = 0; k < 10; ++k) {
        int j = eb + k * 512 + tid;
        if (j < ee) {
            unsigned int p = pk[k];
            srcs[nstart[p >> 17] + rnk[k]] = (int)(p & 0x1FFFFu);
        }
    }
}

// ---------------------------------------------------------------------------
// 3) fused agg1 + gemm1 + gemm2 (measured-best R12 shape: 64 nodes/block,
//    W2 bf16-packed in LDS, no aggt — butterfly leaves sum in all 4 lanes).
//    LDS 52.7 KB. BN=32 regressed (Phase-B fixed cost doubles); W2-__ldg was
//    neutral-to-worse; occupancy pushes beyond this point all failed.
__global__ __launch_bounds__(256) void agg1_gemm12_kernel(
        const float4* __restrict__ xs, const int* __restrict__ offs,
        const int* __restrict__ ends, const int* __restrict__ srcs,
        const float* __restrict__ inv, const float* __restrict__ W1,
        const float* __restrict__ b1, const float* __restrict__ W2,
        unsigned short* __restrict__ hs2b) {
    __shared__ float w1s[4 * C1];                    // 2 KB
    __shared__ float bs[C1];                         // 0.5 KB
    __shared__ unsigned int w2b[C1 * C2 / 2];        // 16 KB (bf16-packed pairs)
    __shared__ float rows[64 * RSTRIDE];             // 33.8 KB
    int tid = threadIdx.x;
    int base = blockIdx.x * 64;
    w1s[tid] = W1[tid];                      // W1 is 512 floats, block is 256:
    w1s[tid + 256] = W1[tid + 256];          // each thread loads BOTH halves
    if (tid < C1) bs[tid] = b1[tid];
    {
        const float2* w2f = (const float2*)W2;
        for (int i = tid; i < C1 * C2 / 2; i += 256) {
            float2 v = w2f[i];
            w2b[i] = (unsigned int)f2bf(v.x) | ((unsigned int)f2bf(v.y) << 16);
        }
    }
    // Phase 0: gather aggX for the block's 64 nodes (4 lanes/node, xs is
    // L2-resident 1.6 MB). Butterfly leaves the sum in all 4 lanes.
    int nd = tid >> 2, g = tid & 3;
    int n = base + nd;
    float4 acc0 = make_float4(0.f, 0.f, 0.f, 0.f);
    {
        if (n < N_NODES) {
            if (g == 0) acc0 = xs[n];
            int e = ends[n];
            for (int j = offs[n] + g; j < e; j += 4)
                acc0 = f4add(acc0, xs[srcs[j]]);
        }
        acc0.x += __shfl_xor(acc0.x, 1); acc0.y += __shfl_xor(acc0.y, 1);
        acc0.z += __shfl_xor(acc0.z, 1); acc0.w += __shfl_xor(acc0.w, 1);
        acc0.x += __shfl_xor(acc0.x, 2); acc0.y += __shfl_xor(acc0.y, 2);
        acc0.z += __shfl_xor(acc0.z, 2); acc0.w += __shfl_xor(acc0.w, 2);
    }
    __syncthreads();          // staging (w1s/bs/w2b) complete
    // Phase A: h1 rows -> LDS. thread = (node nd, part g): channels c = g+4*cc
    {
        float s = (n < N_NODES) ? inv[n] : 0.f;
        float4 t = acc0;
        t.x *= s; t.y *= s; t.z *= s; t.w *= s;
        #pragma unroll 8
        for (int cc = 0; cc < 32; ++cc) {
            int c = g + 4 * cc;
            float h = t.x * w1s[c] + t.y * w1s[C1 + c] + t.z * w1s[2 * C1 + c]
                    + t.w * w1s[3 * C1 + c] + bs[c];
            rows[nd * RSTRIDE + c] = fmaxf(h, 0.f);
        }
    }
    __syncthreads();
    // Phase B: 16 col-quads x 16 node-groups (4 nodes each); W2 unpacked bf16
    int q = tid & 15;
    int ng = tid >> 4;
    float4 acc[4];
    #pragma unroll
    for (int j = 0; j < 4; ++j) acc[j] = make_float4(0.f, 0.f, 0.f, 0.f);
    #pragma unroll 4
    for (int k = 0; k < C1; ++k) {
        uint2 wp = ((const uint2*)w2b)[k * 16 + q];
        float wx = bflo(wp.x), wy = bfhi(wp.x);
        float wz = bflo(wp.y), ww = bfhi(wp.y);
        #pragma unroll
        for (int j = 0; j < 4; ++j) {
            float r = rows[(ng * 4 + j) * RSTRIDE + k];
            acc[j].x += r * wx; acc[j].y += r * wy;
            acc[j].z += r * wz; acc[j].w += r * ww;
        }
    }
    #pragma unroll
    for (int j = 0; j < 4; ++j) {
        int m = base + ng * 4 + j;
        if (m < N_NODES) {
            float s = inv[m];
            ushort4 o;
            o.x = f2bf(acc[j].x * s); o.y = f2bf(acc[j].y * s);
            o.z = f2bf(acc[j].z * s); o.w = f2bf(acc[j].w * s);
            *((ushort4*)(hs2b + (size_t)m * C2) + q) = o;
        }
    }
}

// 4) agg2: one 64-lane wave per node; 8 x 16B-chunk lanes x 8 neighbor slots,
//    2-row unroll (16 rows in flight/wave — measured optimum; plateau at
//    ~62.6 us / 2.83 TB/s TCC across all structural variants tried).
//    zb = bf16( inv*(hs2[n] + sum hs2[src]) + b2 )
__global__ void agg2_kernel(const unsigned short* __restrict__ hs2b,
                            const int* __restrict__ offs, const int* __restrict__ ends,
                            const int* __restrict__ srcs, const float* __restrict__ inv,
                            const float4* __restrict__ b2,
                            unsigned short* __restrict__ zb) {
    int gid = blockIdx.x * blockDim.x + threadIdx.x;
    int n = gid >> 6;
    if (n >= N_NODES) return;
    int lane = gid & 63;
    int q = lane & 7;           // 16B chunk (8 bf16 channels) within the row
    int g = lane >> 3;          // neighbor slot 0..7
    float acc[8] = {0.f, 0.f, 0.f, 0.f, 0.f, 0.f, 0.f, 0.f};
    if (g == 0) {
        uint4 v = *((const uint4*)(hs2b + (size_t)n * C2) + q);
        acc[0] += bflo(v.x); acc[1] += bfhi(v.x);
        acc[2] += bflo(v.y); acc[3] += bfhi(v.y);
        acc[4] += bflo(v.z); acc[5] += bfhi(v.z);
        acc[6] += bflo(v.w); acc[7] += bfhi(v.w);
    }
    int e = ends[n];
    int j = offs[n] + g;
    for (; j + 8 < e; j += 16) {            // both j and j+8 valid
        int s0 = srcs[j];
        int s1 = srcs[j + 8];
        uint4 v0 = *((const uint4*)(hs2b + (size_t)s0 * C2) + q);
        uint4 v1 = *((const uint4*)(hs2b + (size_t)s1 * C2) + q);
        acc[0] += bflo(v0.x); acc[1] += bfhi(v0.x);
        acc[2] += bflo(v0.y); acc[3] += bfhi(v0.y);
        acc[4] += bflo(v0.z); acc[5] += bfhi(v0.z);
        acc[6] += bflo(v0.w); acc[7] += bfhi(v0.w);
        acc[0] += bflo(v1.x); acc[1] += bfhi(v1.x);
        acc[2] += bflo(v1.y); acc[3] += bfhi(v1.y);
        acc[4] += bflo(v1.z); acc[5] += bfhi(v1.z);
        acc[6] += bflo(v1.w); acc[7] += bfhi(v1.w);
    }
    if (j < e) {
        int s0 = srcs[j];
        uint4 v0 = *((const uint4*)(hs2b + (size_t)s0 * C2) + q);
        acc[0] += bflo(v0.x); acc[1] += bfhi(v0.x);
        acc[2] += bflo(v0.y); acc[3] += bfhi(v0.y);
        acc[4] += bflo(v0.z); acc[5] += bfhi(v0.z);
        acc[6] += bflo(v0.w); acc[7] += bfhi(v0.w);
    }
    #pragma unroll
    for (int k = 0; k < 8; ++k) {
        acc[k] += __shfl_xor(acc[k], 8);
        acc[k] += __shfl_xor(acc[k], 16);
        acc[k] += __shfl_xor(acc[k], 32);
    }
    if (g == 0) {
        float s = inv[n];
        float4 b0 = b2[q * 2], b1v = b2[q * 2 + 1];
        float o0 = acc[0] * s + b0.x,  o1 = acc[1] * s + b0.y;
        float o2 = acc[2] * s + b0.z,  o3 = acc[3] * s + b0.w;
        float o4 = acc[4] * s + b1v.x, o5 = acc[5] * s + b1v.y;
        float o6 = acc[6] * s + b1v.z, o7 = acc[7] * s + b1v.w;
        uint4 w;
        w.x = (unsigned int)f2bf(o0) | ((unsigned int)f2bf(o1) << 16);
        w.y = (unsigned int)f2bf(o2) | ((unsigned int)f2bf(o3) << 16);
        w.z = (unsigned int)f2bf(o4) | ((unsigned int)f2bf(o5) << 16);
        w.w = (unsigned int)f2bf(o6) | ((unsigned int)f2bf(o7) << 16);
        ((uint4*)(zb + (size_t)n * C2))[q] = w;
    }
}

// 5) decode: logits[e] = dot(zb[a], zb[b])   (8 lanes/edge, bf16 rows)
__global__ void decode_kernel(const int* __restrict__ eli,
                              const unsigned short* __restrict__ zb,
                              float* __restrict__ out) {
    int gid = blockIdx.x * blockDim.x + threadIdx.x;
    int e = gid >> 3;
    if (e >= N_LBL) return;
    int q = gid & 7;
    int a = eli[e], b = eli[N_LBL + e];
    uint4 va = ((const uint4*)zb)[(size_t)a * 8 + q];
    uint4 vb = ((const uint4*)zb)[(size_t)b * 8 + q];
    float p = bflo(va.x) * bflo(vb.x) + bfhi(va.x) * bfhi(vb.x)
            + bflo(va.y) * bflo(vb.y) + bfhi(va.y) * bfhi(vb.y)
            + bflo(va.z) * bflo(vb.z) + bfhi(va.z) * bfhi(vb.z)
            + bflo(va.w) * bflo(vb.w) + bfhi(va.w) * bfhi(vb.w);
    p += __shfl_xor(p, 4);
    p += __shfl_xor(p, 2);
    p += __shfl_xor(p, 1);
    if (q == 0) out[e] = p;
}

extern "C" void kernel_launch(void* const* d_in, const int* in_sizes, int n_in,
                              void* d_out, int out_size, void* d_ws, size_t ws_size,
                              hipStream_t stream) {
    const float* x  = (const float*)d_in[0];
    const int*   ei = (const int*)d_in[1];
    const int*  eli = (const int*)d_in[2];
    const float* W1 = (const float*)d_in[3];
    const float* b1 = (const float*)d_in[4];
    const float* W2 = (const float*)d_in[5];
    const float* b2 = (const float*)d_in[6];
    float* out = (float*)d_out;

    // workspace layout (all 16B aligned). Total ~59 MB.
    char* p = (char*)d_ws;
    int*   gcursor = (int*)p;   p += 1024 * 4;
    int*   offs    = (int*)p;   p += (size_t)N_NODES * 4;
    int*   ends    = (int*)p;   p += (size_t)N_NODES * 4;
    float* inv     = (float*)p; p += (size_t)N_NODES * 4;
    unsigned int* pairs = (unsigned int*)p; p += (size_t)NBKT * CAP * 4;  // 15.6 MB
    int*   srcs    = (int*)p;   p += (size_t)NBKT * CAP * 4;              // 15.6 MB
    float* xs      = (float*)p; p += (size_t)N_NODES * 16;
    unsigned short* hs2b = (unsigned short*)p; p += (size_t)N_NODES * C2 * 2; // 12.8 MB
    unsigned short* zb   = (unsigned short*)p; p += (size_t)N_NODES * C2 * 2; // 12.8 MB

    hipMemsetAsync(gcursor, 0, NBKT * 4, stream);
    pair_place_kernel<<<NCB, PPT, 0, stream>>>(ei, gcursor, pairs);
    bucket_finish_kernel<<<NBKT, 512, 0, stream>>>(pairs, gcursor, (const float4*)x,
                                                   offs, ends, inv, (float4*)xs, srcs);
    agg1_gemm12_kernel<<<(N_NODES + 63) / 64, 256, 0, stream>>>(
        (const float4*)xs, offs, ends, srcs, inv, W1, b1, W2, hs2b);
    agg2_kernel<<<((size_t)N_NODES * 64 + 255) / 256, 256, 0, stream>>>(
        hs2b, offs, ends, srcs, inv, (const float4*)b2, zb);
    decode_kernel<<<((size_t)N_LBL * 8 + 255) / 256, 256, 0, stream>>>(eli, zb, out);
}